// Round 4
// baseline (67.338 us; speedup 1.0000x reference)
//
#include <hip/hip_runtime.h>
#include <math.h>

#define BB   512
#define CC   3
#define HH   64
#define WW   32
#define HOUT 38
#define WOUT 16
#define HID  128
#define DD   114          // CC*HOUT
#define DP   116          // padded act row (116*4B = 464 B, 16B-aligned)
#define NPOOL (CC*HOUT*WOUT) // 1824
#define WPAD 132          // padded Whh LDS row (132*4B, 16B-aligned, bank-friendly)

typedef float f32x4 __attribute__((ext_vector_type(4)));

// ws layout (floats)
#define WS_SMEAN 0
#define WS_TMEAN 512
#define WS_ACT   (512 + BB*HID)                  // act[t][b][DP]
#define WS_Z     (WS_ACT + WOUT*BB*DP)           // Z[t][b][HID]

// ---------------- k1a: pool + exact GELU + s_mean -------------------------
__global__ __launch_bounds__(256)
void k1a_pool(const float* __restrict__ x, float* __restrict__ act,
              float* __restrict__ s_mean)
{
    __shared__ __align__(16) float xl[CC*HH*WW];   // 24 KB
    __shared__ float red[256];
    __shared__ int   rowl[HOUT];

    const int tid = threadIdx.x;
    const int b   = blockIdx.x;

    if (tid < HOUT) {
        double alpha = (double)(HH - 2) / (double)(HOUT - 1);
        rowl[tid] = (tid < HOUT - 1)
            ? (int)(floor((tid + 0.5) * alpha) - floor(0.5 * alpha))
            : (HH - 2);
    }
    {
        const float4* xg  = (const float4*)(x + (size_t)b * (CC*HH*WW));
        float4*       xl4 = (float4*)xl;
        #pragma unroll
        for (int i = 0; i < (CC*HH*WW/4)/256; ++i)
            xl4[tid + 256*i] = xg[tid + 256*i];
    }
    // zero the 2 pad lanes of each of the 16 act rows for this b
    if (tid < 32) {
        int t = tid >> 1, d = DD + (tid & 1);
        act[(size_t)(t*BB + b)*DP + d] = 0.f;
    }
    __syncthreads();

    float psum = 0.f;
    for (int idx = tid; idx < NPOOL; idx += 256) {
        int c  = idx / (HOUT*WOUT);
        int r  = idx % (HOUT*WOUT);
        int ho = r / WOUT;
        int wo = r % WOUT;
        const float* p0 = &xl[c*(HH*WW) + rowl[ho]*WW + 2*wo];
        float m = fmaxf(fmaxf(p0[0], p0[1]), fmaxf(p0[WW], p0[WW+1]));
        psum += m;
        float a = 0.5f * m * (1.f + erff(m * 0.70710678118654752440f));
        act[(size_t)(wo*BB + b)*DP + c*HOUT + ho] = a;
    }
    red[tid] = psum;
    __syncthreads();
    #pragma unroll
    for (int s = 128; s > 0; s >>= 1) {
        if (tid < s) red[tid] += red[tid + s];
        __syncthreads();
    }
    if (tid == 0) s_mean[b] = red[0] / (float)NPOOL;
}

// ---------------- k1b: Z[t][b][k] = act[t][b][:] . Wih[k][:] + bias -------
// grid: (32 bgroups, 16 t), 128 threads (thread = k), 16 batches per block
#define GBAT 16
__global__ __launch_bounds__(128, 2)
void k1b_proj(const float* __restrict__ act, const float* __restrict__ Wih,
              const float* __restrict__ bih, const float* __restrict__ bhh,
              float* __restrict__ Z)
{
    __shared__ __align__(16) float wl[HID][DP];     // 128x116 f = 59.4 KB
    __shared__ __align__(16) float actl[GBAT][DP];  // 7.4 KB

    const int k  = threadIdx.x;
    const int bg = blockIdx.x;
    const int t  = blockIdx.y;

    // coalesced stage of Wih into padded LDS rows
    for (int j = k; j < HID*DD; j += 128) {
        int r = j / DD, c = j - r*DD;
        wl[r][c] = Wih[j];
    }
    for (int j = k; j < HID*2; j += 128)
        wl[j >> 1][DD + (j & 1)] = 0.f;

    // stage 16 act rows (contiguous 1856 floats, 16B-aligned)
    {
        const float4* src = (const float4*)(act + (size_t)(t*BB + bg*GBAT)*DP);
        float4*       dst = (float4*)&actl[0][0];
        for (int j = k; j < GBAT*DP/4; j += 128) dst[j] = src[j];
    }
    __syncthreads();

    // Wih row k -> registers (one-time, ~4-way LDS conflict acceptable)
    float4 wih[29];
    {
        const float4* wr = (const float4*)wl[k];
        #pragma unroll
        for (int dd = 0; dd < 29; ++dd) wih[dd] = wr[dd];
    }
    const float bias = bih[k] + bhh[k];

    #pragma unroll 4
    for (int r = 0; r < GBAT; ++r) {
        const float4* a4 = (const float4*)actl[r];
        float s0 = 0.f, s1 = 0.f, s2 = 0.f, s3 = 0.f;
        #pragma unroll
        for (int dd = 0; dd < 29; ++dd) {
            float4 a = a4[dd];
            s0 = fmaf(wih[dd].x, a.x, s0);
            s1 = fmaf(wih[dd].y, a.y, s1);
            s2 = fmaf(wih[dd].z, a.z, s2);
            s3 = fmaf(wih[dd].w, a.w, s3);
        }
        Z[(size_t)(t*BB + bg*GBAT + r)*HID + k] = bias + ((s0+s1)+(s2+s3));
    }
}

// ---------------- k1c: 16-step recurrence + t_mean (split-K over 2 halves) -
__global__ __launch_bounds__(256, 2)
void k1c_rnn(const float* __restrict__ Z, const float* __restrict__ Whh,
             float* __restrict__ t_mean)
{
    __shared__ __align__(16) float wl[HID][WPAD];   // 67.6 KB
    __shared__ __align__(16) float Zl[WOUT][HID];   // 8 KB
    __shared__ __align__(16) float hbuf[2][HID];    // 1 KB
    __shared__ float psum[HID];                     // 0.5 KB

    const int tid  = threadIdx.x;
    const int half = tid >> 7;
    const int k    = tid & 127;
    const int b    = blockIdx.x;

    // stage Whh coalesced: 4096 f4, row r = j>>5, col-quad c4 = j&31
    {
        const float4* src = (const float4*)Whh;
        for (int j = tid; j < (HID*HID)/4; j += 256) {
            int r = j >> 5, c4 = j & 31;
            *(float4*)&wl[r][c4 << 2] = src[j];
        }
    }
    // stage Z for this batch: 512 f4 (t = j>>5)
    for (int j = tid; j < (WOUT*HID)/4; j += 256) {
        int t = j >> 5, c4 = j & 31;
        ((float4*)&Zl[t][0])[c4] =
            ((const float4*)(Z + (size_t)(t*BB + b)*HID))[c4];
    }
    if (tid < HID) hbuf[0][tid] = 0.f;
    __syncthreads();

    // half-row of Whh -> 16 float4 = 64 VGPR (no spill)
    float4 whh[16];
    {
        const float4* wr = (const float4*)&wl[k][half << 6];
        #pragma unroll
        for (int dd = 0; dd < 16; ++dd) whh[dd] = wr[dd];
    }

    float hsum = 0.f;
    #pragma unroll
    for (int t = 0; t < WOUT; ++t) {
        const int cur = t & 1, nxt = cur ^ 1;
        const float4* h4 = (const float4*)&hbuf[cur][half << 6]; // wave-uniform: broadcast
        float s0 = 0.f, s1 = 0.f, s2 = 0.f, s3 = 0.f;
        #pragma unroll
        for (int dd = 0; dd < 16; ++dd) {
            float4 hv = h4[dd];
            s0 = fmaf(whh[dd].x, hv.x, s0);
            s1 = fmaf(whh[dd].y, hv.y, s1);
            s2 = fmaf(whh[dd].z, hv.z, s2);
            s3 = fmaf(whh[dd].w, hv.w, s3);
        }
        float up = (s0 + s1) + (s2 + s3);
        if (half) psum[k] = up;
        __syncthreads();
        if (!half) {
            float hn = tanhf(Zl[t][k] + up + psum[k]);
            hsum += hn;
            hbuf[nxt][k] = hn;
        }
        __syncthreads();
    }
    if (!half) t_mean[b*HID + k] = tanhf(hsum * (1.f / 16.f));
}

// ---------------- k2: out[i,0,j,k] = s_mean[i] * t_mean[j,k] --------------
__global__ __launch_bounds__(256)
void k2_out(const float* __restrict__ s_mean,
            const float* __restrict__ t_mean,
            f32x4* __restrict__ out)
{
    const int total = BB * BB * HID / 4;        // 8,388,608 float4
    const f32x4* t4 = (const f32x4*)t_mean;
    const int stride = gridDim.x * blockDim.x;
    for (int g = blockIdx.x * blockDim.x + threadIdx.x; g < total; g += stride) {
        int i = g >> 14;                        // 16384 f4 per i
        int r = g & 16383;
        float s = s_mean[i];
        f32x4 t = t4[r];
        f32x4 v = s * t;
        __builtin_nontemporal_store(v, &out[g]);
    }
}

extern "C" void kernel_launch(void* const* d_in, const int* in_sizes, int n_in,
                              void* d_out, int out_size, void* d_ws, size_t ws_size,
                              hipStream_t stream)
{
    const float* x   = (const float*)d_in[0];
    const float* Wih = (const float*)d_in[1];
    const float* Whh = (const float*)d_in[2];
    const float* bih = (const float*)d_in[3];
    const float* bhh = (const float*)d_in[4];

    float* ws     = (float*)d_ws;
    float* s_mean = ws + WS_SMEAN;
    float* t_mean = ws + WS_TMEAN;
    float* act    = ws + WS_ACT;
    float* Z      = ws + WS_Z;

    k1a_pool<<<dim3(BB), dim3(256), 0, stream>>>(x, act, s_mean);
    k1b_proj<<<dim3(BB/GBAT, WOUT), dim3(128), 0, stream>>>(act, Wih, bih, bhh, Z);
    k1c_rnn <<<dim3(BB), dim3(256), 0, stream>>>(Z, Whh, t_mean);
    k2_out  <<<dim3(4096), dim3(256), 0, stream>>>(s_mean, t_mean, (f32x4*)d_out);
}

// Round 5
// 66.935 us; speedup vs baseline: 1.0060x; 1.0060x over previous
//
#include <hip/hip_runtime.h>
#include <math.h>

#define BB   512
#define CC   3
#define HH   64
#define WW   32
#define HOUT 38
#define WOUT 16
#define HID  128
#define DD   114              // CC*HOUT
#define DP2  120              // seq row padded to 120 f (30 f4) -> two 15-f4 halves
#define NPOOL (CC*HOUT*WOUT)  // 1824

typedef float f32x4 __attribute__((ext_vector_type(4)));

// ws layout (floats)
#define WS_SMEAN 0
#define WS_TMEAN 512

// ---- fused per-batch kernel: pool+GELU+s_mean -> proj -> 16-step RNN -> t_mean
// 256 threads: tid = (half<<7)|k ; thread (k,half) owns half of Wih row k and
// half of Whh row k in registers (60+64 VGPR, no spill at launch_bounds(256,2)).
__global__ __launch_bounds__(256, 2)
void k1_fused(const float* __restrict__ x,
              const float* __restrict__ Wih,
              const float* __restrict__ Whh,
              const float* __restrict__ bih,
              const float* __restrict__ bhh,
              float* __restrict__ s_mean,
              float* __restrict__ t_mean)
{
    __shared__ __align__(16) float xl[CC*HH*WW];    // 24 KB
    __shared__ __align__(16) float seq[WOUT][DP2];  // 7.7 KB
    __shared__ __align__(16) float Zl[WOUT][HID];   // 8 KB
    __shared__ __align__(16) float hbuf[2][HID];    // 1 KB
    __shared__ float red[256];                      // 1 KB
    __shared__ int   rowl[HOUT];

    const int tid  = threadIdx.x;
    const int half = tid >> 7;
    const int k    = tid & 127;
    const int b    = blockIdx.x;

    // --- weights into registers (L2-broadcast reads, same for every block) ---
    f32x4 wih[15];                      // floats [half*60, half*60+60) of Wih row k
    #pragma unroll
    for (int dd = 0; dd < 15; ++dd) {
        float v0, v1, v2, v3;
        int base = half*60 + dd*4;
        v0 = (base+0 < DD) ? Wih[k*DD + base+0] : 0.f;
        v1 = (base+1 < DD) ? Wih[k*DD + base+1] : 0.f;
        v2 = (base+2 < DD) ? Wih[k*DD + base+2] : 0.f;
        v3 = (base+3 < DD) ? Wih[k*DD + base+3] : 0.f;
        wih[dd] = (f32x4){v0, v1, v2, v3};
    }
    f32x4 whh[16];                      // floats [half*64, half*64+64) of Whh row k
    {
        const f32x4* wr = (const f32x4*)(Whh + k*HID + (half << 6));
        #pragma unroll
        for (int dd = 0; dd < 16; ++dd) whh[dd] = wr[dd];
    }
    const float bias = bih[k] + bhh[k];

    // --- fractional-pool row starts (exact IEEE-f64 numpy match) ---
    if (tid < HOUT) {
        double alpha = (double)(HH - 2) / (double)(HOUT - 1);
        rowl[tid] = (tid < HOUT - 1)
            ? (int)(floor((tid + 0.5) * alpha) - floor(0.5 * alpha))
            : (HH - 2);
    }
    // --- stage x[b] (coalesced f4) ---
    {
        const f32x4* xg  = (const f32x4*)(x + (size_t)b * (CC*HH*WW));
        f32x4*       xl4 = (f32x4*)xl;
        #pragma unroll
        for (int i = 0; i < (CC*HH*WW/4)/256; ++i)
            xl4[tid + 256*i] = xg[tid + 256*i];
    }
    if (tid < 96) seq[tid / 6][DD + tid % 6] = 0.f;   // zero 6 pad lanes x 16 rows
    if (tid < HID) hbuf[0][tid] = 0.f;
    __syncthreads();

    // --- pool (2x2 fractional max) + exact GELU -> seq, and spatial sum ---
    float psum = 0.f;
    for (int idx = tid; idx < NPOOL; idx += 256) {
        int c  = idx / (HOUT*WOUT);
        int r  = idx % (HOUT*WOUT);
        int ho = r / WOUT;
        int wo = r % WOUT;
        const float* p0 = &xl[c*(HH*WW) + rowl[ho]*WW + 2*wo];
        float m = fmaxf(fmaxf(p0[0], p0[1]), fmaxf(p0[WW], p0[WW+1]));
        psum += m;
        seq[wo][c*HOUT + ho] = 0.5f * m * (1.f + erff(m * 0.70710678118654752440f));
    }
    red[tid] = psum;
    __syncthreads();
    #pragma unroll
    for (int s = 128; s > 0; s >>= 1) {
        if (tid < s) red[tid] += red[tid + s];
        __syncthreads();
    }
    if (tid == 0) s_mean[b] = red[0] / (float)NPOOL;

    // --- projection: Zl[t][k] = seq[t][:] . Wih[k][:] + bias (split-K) ---
    float zp[WOUT];
    #pragma unroll
    for (int t = 0; t < WOUT; ++t) {
        const f32x4* a4 = (const f32x4*)&seq[t][0] + half*15;  // wave-uniform addr
        float s0 = 0.f, s1 = 0.f, s2 = 0.f, s3 = 0.f;
        #pragma unroll
        for (int dd = 0; dd < 15; ++dd) {
            f32x4 a = a4[dd];
            s0 = fmaf(wih[dd].x, a.x, s0);
            s1 = fmaf(wih[dd].y, a.y, s1);
            s2 = fmaf(wih[dd].z, a.z, s2);
            s3 = fmaf(wih[dd].w, a.w, s3);
        }
        zp[t] = (s0 + s1) + (s2 + s3);
    }
    if (half) {
        #pragma unroll
        for (int t = 0; t < WOUT; ++t) Zl[t][k] = zp[t];
    }
    __syncthreads();
    if (!half) {
        #pragma unroll
        for (int t = 0; t < WOUT; ++t) Zl[t][k] += bias + zp[t];
    }
    __syncthreads();

    // --- 16-step recurrence (split-K, h broadcast from LDS) ---
    float hsum = 0.f;
    #pragma unroll
    for (int t = 0; t < WOUT; ++t) {
        const int cur = t & 1, nxt = cur ^ 1;
        const f32x4* h4 = (const f32x4*)&hbuf[cur][half << 6];
        float s0 = 0.f, s1 = 0.f, s2 = 0.f, s3 = 0.f;
        #pragma unroll
        for (int dd = 0; dd < 16; ++dd) {
            f32x4 hv = h4[dd];
            s0 = fmaf(whh[dd].x, hv.x, s0);
            s1 = fmaf(whh[dd].y, hv.y, s1);
            s2 = fmaf(whh[dd].z, hv.z, s2);
            s3 = fmaf(whh[dd].w, hv.w, s3);
        }
        float up = (s0 + s1) + (s2 + s3);
        if (half) red[k] = up;
        __syncthreads();
        if (!half) {
            float hn = tanhf(Zl[t][k] + up + red[k]);
            hsum += hn;
            hbuf[nxt][k] = hn;
        }
        __syncthreads();
    }
    if (!half) t_mean[b*HID + k] = tanhf(hsum * (1.f / 16.f));
}

// ---- k2: out[i,0,j,kk] = s_mean[i] * t_mean[j,kk] (134 MB stream, nt stores)
__global__ __launch_bounds__(256)
void k2_out(const float* __restrict__ s_mean,
            const float* __restrict__ t_mean,
            f32x4* __restrict__ out)
{
    const int total = BB * BB * HID / 4;        // 8,388,608 f4
    const f32x4* t4 = (const f32x4*)t_mean;
    const int stride = gridDim.x * blockDim.x;
    for (int g = blockIdx.x * blockDim.x + threadIdx.x; g < total; g += stride) {
        int i = g >> 14;                        // 16384 f4 per i
        int r = g & 16383;
        float s = s_mean[i];
        f32x4 t = t4[r];
        f32x4 v = s * t;
        __builtin_nontemporal_store(v, &out[g]);
    }
}

extern "C" void kernel_launch(void* const* d_in, const int* in_sizes, int n_in,
                              void* d_out, int out_size, void* d_ws, size_t ws_size,
                              hipStream_t stream)
{
    const float* x   = (const float*)d_in[0];
    const float* Wih = (const float*)d_in[1];
    const float* Whh = (const float*)d_in[2];
    const float* bih = (const float*)d_in[3];
    const float* bhh = (const float*)d_in[4];

    float* ws     = (float*)d_ws;
    float* s_mean = ws + WS_SMEAN;
    float* t_mean = ws + WS_TMEAN;

    k1_fused<<<dim3(BB), dim3(256), 0, stream>>>(x, Wih, Whh, bih, bhh, s_mean, t_mean);
    k2_out  <<<dim3(4096), dim3(256), 0, stream>>>(s_mean, t_mean, (f32x4*)d_out);
}

// Round 6
// 53.773 us; speedup vs baseline: 1.2523x; 1.2448x over previous
//
#include <hip/hip_runtime.h>
#include <math.h>

#define BB   512
#define CC   3
#define HH   64
#define WW   32
#define HOUT 38
#define WOUT 16
#define HID  128
#define DD   114               // CC*HOUT
#define SEQP 120               // seq row pad: two 60-float (15 f4) halves
#define WROW 132               // weight LDS row pad (132 ≡ 4 mod 32 -> 8-way max)
#define NPOOL (CC*HOUT*WOUT)   // 1824

typedef float f32x4 __attribute__((ext_vector_type(4)));

// ws layout (floats)
#define WS_SMEAN 0
#define WS_TMEAN 512

// ---- fused per-batch kernel ------------------------------------------------
// 256 threads: tid = (half<<7)|k. Thread (k,half) holds half of Wih row k
// (15 f4) and half of Whh row k (16 f4) in registers; weights arrive via
// COALESCED global->LDS staging (4 chunks of 64 rows through a 33 KB buffer
// that reuses the x-staging region), never via lane-divergent gathers.
__global__ __launch_bounds__(256, 2)
void k1_fused(const float* __restrict__ x,
              const float* __restrict__ Wih,
              const float* __restrict__ Whh,
              const float* __restrict__ bih,
              const float* __restrict__ bhh,
              float* __restrict__ s_mean,
              float* __restrict__ t_mean)
{
    __shared__ __align__(16) float wst[64 * WROW];   // 33 KB; also x-stage region
    __shared__ __align__(16) float seq[WOUT][SEQP];  // 7.5 KB
    __shared__ __align__(16) float Zl[WOUT][HID];    // 8 KB
    __shared__ __align__(16) float hbuf[2][HID];     // 1 KB
    __shared__ float psum[HID];
    __shared__ float red[256];
    __shared__ int   rowl[HOUT];

    const int tid  = threadIdx.x;
    const int half = tid >> 7;
    const int k    = tid & 127;
    const int b    = blockIdx.x;

    // fractional-pool row starts (exact IEEE-f64 numpy match)
    if (tid < HOUT) {
        double alpha = (double)(HH - 2) / (double)(HOUT - 1);
        rowl[tid] = (tid < HOUT - 1)
            ? (int)(floor((tid + 0.5) * alpha) - floor(0.5 * alpha))
            : (HH - 2);
    }
    if (tid < HID) hbuf[0][tid] = 0.f;
    if (tid < 96)  seq[tid / 6][DD + tid % 6] = 0.f;  // zero pad lanes [114,120)

    // --- stage x[b] into wst (coalesced f4) ---
    {
        const f32x4* xg = (const f32x4*)(x + (size_t)b * (CC*HH*WW));
        f32x4*       xd = (f32x4*)wst;
        #pragma unroll
        for (int i = 0; i < (CC*HH*WW/4)/256; ++i)
            xd[tid + 256*i] = xg[tid + 256*i];
    }
    __syncthreads();

    // --- pool (2x2 fractional max) + exact GELU -> seq; spatial sum ---
    float ps = 0.f;
    #pragma unroll
    for (int it = 0; it < 8; ++it) {
        int idx = tid + it*256;
        if (idx < NPOOL) {
            int c  = idx / (HOUT*WOUT);
            int r  = idx % (HOUT*WOUT);
            int ho = r / WOUT;
            int wo = r % WOUT;
            const float* p0 = &wst[c*(HH*WW) + rowl[ho]*WW + 2*wo];
            float m = fmaxf(fmaxf(p0[0], p0[1]), fmaxf(p0[WW], p0[WW+1]));
            ps += m;
            seq[wo][c*HOUT + ho] =
                0.5f * m * (1.f + erff(m * 0.70710678118654752440f));
        }
    }
    red[tid] = ps;
    __syncthreads();
    #pragma unroll
    for (int s = 128; s > 0; s >>= 1) {
        if (tid < s) red[tid] += red[tid + s];
        __syncthreads();
    }
    if (tid == 0) s_mean[b] = red[0] / (float)NPOOL;
    __syncthreads();   // wst (x copy) now dead; safe to reuse for weights

    // --- weights: coalesced global -> LDS chunks -> registers ---
    f32x4 wih[15];
    f32x4 whh[16];

    #pragma unroll
    for (int c = 0; c < 2; ++c) {          // Wih rows [64c, 64c+64)
        const f32x4* g4 = (const f32x4*)(Wih + c*64*DD);
        for (int j4 = tid; j4 < (64*DD)/4; j4 += 256) {
            f32x4 v = g4[j4];
            int j = 4*j4;
            #pragma unroll
            for (int e = 0; e < 4; ++e) {
                int r  = (j + e) / DD;     // const-div -> magic mul
                int cc = (j + e) - r*DD;
                wst[r*WROW + cc] = v[e];
            }
        }
        for (int j = tid; j < 64*6; j += 256)        // zero cols [114,120)
            wst[(j/6)*WROW + DD + (j % 6)] = 0.f;
        __syncthreads();
        if ((k >> 6) == c) {
            const f32x4* wr = (const f32x4*)&wst[(k & 63)*WROW + half*60];
            #pragma unroll
            for (int dd = 0; dd < 15; ++dd) wih[dd] = wr[dd];
        }
        __syncthreads();
    }
    #pragma unroll
    for (int c = 0; c < 2; ++c) {          // Whh rows [64c, 64c+64)
        const f32x4* g4 = (const f32x4*)(Whh + c*64*HID);
        for (int j4 = tid; j4 < (64*HID)/4; j4 += 256) {
            int r  = j4 >> 5;              // 32 f4 per row
            int c4 = j4 & 31;
            *(f32x4*)&wst[r*WROW + (c4 << 2)] = g4[j4];
        }
        __syncthreads();
        if ((k >> 6) == c) {
            const f32x4* wr = (const f32x4*)&wst[(k & 63)*WROW + (half << 6)];
            #pragma unroll
            for (int dd = 0; dd < 16; ++dd) whh[dd] = wr[dd];
        }
        __syncthreads();
    }

    // --- projection: z[t] (kept in half-0 registers) ---
    float zreg[WOUT];
    #pragma unroll
    for (int t = 0; t < WOUT; ++t) {
        const f32x4* a4 = (const f32x4*)&seq[t][half*60];  // wave-uniform bcast
        float s0 = 0.f, s1 = 0.f, s2 = 0.f, s3 = 0.f;
        #pragma unroll
        for (int dd = 0; dd < 15; ++dd) {
            f32x4 a = a4[dd];
            s0 = fmaf(wih[dd].x, a.x, s0);
            s1 = fmaf(wih[dd].y, a.y, s1);
            s2 = fmaf(wih[dd].z, a.z, s2);
            s3 = fmaf(wih[dd].w, a.w, s3);
        }
        float zp = (s0 + s1) + (s2 + s3);
        if (half) Zl[t][k] = zp; else zreg[t] = zp;
    }
    __syncthreads();
    const float bias = bih[k] + bhh[k];    // lane-consecutive, coalesced
    if (!half) {
        #pragma unroll
        for (int t = 0; t < WOUT; ++t) zreg[t] += bias + Zl[t][k];
    }

    // --- 16-step recurrence (split-K; h broadcast from LDS) ---
    float hsum = 0.f;
    #pragma unroll
    for (int t = 0; t < WOUT; ++t) {
        const int cur = t & 1, nxt = cur ^ 1;
        const f32x4* h4 = (const f32x4*)&hbuf[cur][half << 6];  // bcast
        float s0 = 0.f, s1 = 0.f, s2 = 0.f, s3 = 0.f;
        #pragma unroll
        for (int dd = 0; dd < 16; ++dd) {
            f32x4 hv = h4[dd];
            s0 = fmaf(whh[dd].x, hv.x, s0);
            s1 = fmaf(whh[dd].y, hv.y, s1);
            s2 = fmaf(whh[dd].z, hv.z, s2);
            s3 = fmaf(whh[dd].w, hv.w, s3);
        }
        float up = (s0 + s1) + (s2 + s3);
        if (half) psum[k] = up;
        __syncthreads();
        if (!half) {
            float hn = tanhf(zreg[t] + up + psum[k]);
            hsum += hn;
            hbuf[nxt][k] = hn;
        }
        __syncthreads();
    }
    if (!half) t_mean[b*HID + k] = tanhf(hsum * (1.f / 16.f));
}

// ---- k2: out[i,0,j,kk] = s_mean[i] * t_mean[j,kk]  (plain streaming stores) -
__global__ __launch_bounds__(256)
void k2_out(const float* __restrict__ s_mean,
            const float* __restrict__ t_mean,
            f32x4* __restrict__ out)
{
    const int total = BB * BB * HID / 4;        // 8,388,608 f4
    const f32x4* t4 = (const f32x4*)t_mean;
    const int stride = gridDim.x * blockDim.x;
    for (int g = blockIdx.x * blockDim.x + threadIdx.x; g < total; g += stride) {
        int i = g >> 14;                        // 16384 f4 per i
        int r = g & 16383;
        float s = s_mean[i];
        f32x4 t = t4[r];
        out[g] = s * t;
    }
}

extern "C" void kernel_launch(void* const* d_in, const int* in_sizes, int n_in,
                              void* d_out, int out_size, void* d_ws, size_t ws_size,
                              hipStream_t stream)
{
    const float* x   = (const float*)d_in[0];
    const float* Wih = (const float*)d_in[1];
    const float* Whh = (const float*)d_in[2];
    const float* bih = (const float*)d_in[3];
    const float* bhh = (const float*)d_in[4];

    float* ws     = (float*)d_ws;
    float* s_mean = ws + WS_SMEAN;
    float* t_mean = ws + WS_TMEAN;

    k1_fused<<<dim3(BB), dim3(256), 0, stream>>>(x, Wih, Whh, bih, bhh, s_mean, t_mean);
    k2_out  <<<dim3(4096), dim3(256), 0, stream>>>(s_mean, t_mean, (f32x4*)d_out);
}